// Round 10
// baseline (136.212 us; speedup 1.0000x reference)
//
#include <hip/hip_runtime.h>
#include <hip/hip_fp8.h>

// out[i] = z[i] - COEFF*(2/N)*nf[i]*g[i],  g[i] = deg(i)*zr[i] - sum_{adj} zr[j],
// zr[j] = nf[j]*z[j].  adj counts both edge directions.
//
// Pipeline (no global atomics):
//  1) count (+fused fp8 zr precompute): per-block LDS hist of node>>6
//  2) scan:      exclusive scan -> S (deterministic bucket bases)
//  3) partition: pack (il<<obits | other) into 64-node bucket regions (LDS bump)
//  4) bucket_sort_gather: block per 64-node bucket; hist -> scan -> place into
//     LDS adjl, then register fp8 gather + fused finalize.
// RANGE=64 / IPB=4096 chosen for TLP: 1563 fused blocks (~6/CU), 782 build
// blocks (~3/CU). r9 at RANGE=128 was grid-starved (26% occupancy).

#define RANGE_SHIFT 6
#define RANGE 64
#define IPB 4096
#define SCAN_CHUNK 2048
#define MAX_BUCKETS 2048
#define CAP 2560

typedef float f32x2 __attribute__((ext_vector_type(2)));

static __device__ __forceinline__ unsigned char f2fp8(float f) {
    __hip_fp8_e4m3 h(f);
    return (unsigned char)h.__x;
}
static __device__ __forceinline__ float fp82f_sw(unsigned char b) {
    __hip_fp8_e4m3 h; h.__x = (__hip_fp8_storage_t)b; return (float)h;
}
static __device__ __forceinline__ float4 fp8x4_to_f32(unsigned v) {
#if __has_builtin(__builtin_amdgcn_cvt_pk_f32_fp8)
    f32x2 lo = __builtin_amdgcn_cvt_pk_f32_fp8(v, false);
    f32x2 hi = __builtin_amdgcn_cvt_pk_f32_fp8(v, true);
    return make_float4(lo[0], lo[1], hi[0], hi[1]);
#else
    return make_float4(fp82f_sw((unsigned char)(v & 0xFF)),
                       fp82f_sw((unsigned char)((v >> 8) & 0xFF)),
                       fp82f_sw((unsigned char)((v >> 16) & 0xFF)),
                       fp82f_sw((unsigned char)(v >> 24)));
#endif
}

// count + fused zr8 precompute (independent work, hides under hist latency)
__global__ __launch_bounds__(256) void count_kernel(const int* __restrict__ ei,
        int* __restrict__ counts, int twoE, int npart, int nbuck,
        const float4* __restrict__ z4, const float* __restrict__ nf,
        uchar4* __restrict__ zr8, int C, long totalP) {
    __shared__ int lcnt[MAX_BUCKETS];
    for (int k = threadIdx.x; k < nbuck; k += 256) lcnt[k] = 0;
    __syncthreads();
    // fused precompute slice (grid-stride over npart blocks)
    for (long t = (long)blockIdx.x * 256 + threadIdx.x; t < totalP;
         t += (long)npart * 256) {
        int node = (int)(t / C);
        float s = nf[node];
        float4 v = z4[t];
        uchar4 q;
        q.x = f2fp8(s * v.x); q.y = f2fp8(s * v.y);
        q.z = f2fp8(s * v.z); q.w = f2fp8(s * v.w);
        zr8[t] = q;
    }
    int base = blockIdx.x * IPB;
    int endt = min(base + IPB, twoE);
    for (int t = base + threadIdx.x; t < endt; t += 256)
        atomicAdd(&lcnt[ei[t] >> RANGE_SHIFT], 1);
    __syncthreads();
    for (int k = threadIdx.x; k < nbuck; k += 256)
        counts[k * npart + blockIdx.x] = lcnt[k];
}

__global__ __launch_bounds__(256) void scan_block_sums(const int* __restrict__ deg,
                                                       int* __restrict__ bsum, int N) {
    __shared__ int lds[256];
    int base = blockIdx.x * SCAN_CHUNK;
    int s = 0;
    #pragma unroll
    for (int k = 0; k < 8; ++k) {
        int i = base + k * 256 + threadIdx.x;
        if (i < N) s += deg[i];
    }
    lds[threadIdx.x] = s;
    __syncthreads();
    for (int off = 128; off > 0; off >>= 1) {
        if (threadIdx.x < off) lds[threadIdx.x] += lds[threadIdx.x + off];
        __syncthreads();
    }
    if (threadIdx.x == 0) bsum[blockIdx.x] = lds[0];
}

__global__ void scan_bsums(const int* __restrict__ bsum, int* __restrict__ boff, int NB) {
    __shared__ int lds[1024];
    for (int i = threadIdx.x; i < 1024; i += blockDim.x) lds[i] = (i < NB) ? bsum[i] : 0;
    __syncthreads();
    if (threadIdx.x == 0) {
        int run = 0;
        for (int i = 0; i < NB; ++i) { int v = lds[i]; lds[i] = run; run += v; }
    }
    __syncthreads();
    for (int i = threadIdx.x; i < NB; i += blockDim.x) boff[i] = lds[i];
}

__global__ __launch_bounds__(256) void scan_chunks(const int* __restrict__ deg,
                                                   const int* __restrict__ boff,
                                                   int* __restrict__ starts, int N) {
    __shared__ int buf[SCAN_CHUNK];
    __shared__ int tsum[256];
    int base = blockIdx.x * SCAN_CHUNK;
    #pragma unroll
    for (int k = 0; k < 8; ++k) {
        int i = base + k * 256 + threadIdx.x;
        buf[k * 256 + threadIdx.x] = (i < N) ? deg[i] : 0;
    }
    __syncthreads();
    int lo = threadIdx.x * 8;
    int s = 0;
    #pragma unroll
    for (int k = 0; k < 8; ++k) s += buf[lo + k];
    tsum[threadIdx.x] = s;
    __syncthreads();
    for (int off = 1; off < 256; off <<= 1) {
        int a = tsum[threadIdx.x];
        int b = (threadIdx.x >= (unsigned)off) ? tsum[threadIdx.x - off] : 0;
        __syncthreads();
        tsum[threadIdx.x] = a + b;
        __syncthreads();
    }
    int run = boff[blockIdx.x] + (tsum[threadIdx.x] - s);
    #pragma unroll
    for (int k = 0; k < 8; ++k) {
        int i = base + lo + k;
        if (i < N) starts[i] = run;
        run += buf[lo + k];
    }
}

__global__ __launch_bounds__(256) void partition_kernel(const int* __restrict__ ei,
        const int* __restrict__ S, unsigned* __restrict__ pack,
        int E, int npart, int nbuck, int obits) {
    __shared__ int lbase[MAX_BUCKETS];
    for (int k = threadIdx.x; k < nbuck; k += 256)
        lbase[k] = S[k * npart + blockIdx.x];
    __syncthreads();
    int twoE = 2 * E;
    int base = blockIdx.x * IPB;
    int endt = min(base + IPB, twoE);
    for (int t = base + threadIdx.x; t < endt; t += 256) {
        int node  = ei[t];
        int other = (t < E) ? ei[t + E] : ei[t - E];
        int pos = atomicAdd(&lbase[node >> RANGE_SHIFT], 1);
        pack[pos] = ((unsigned)(node & (RANGE - 1)) << obits) | (unsigned)other;
    }
}

// Fused: in-LDS counting sort of own bucket region + fp8 register gather + finalize.
__global__ __launch_bounds__(256) void bucket_sort_gather(
        const float4* __restrict__ z4, const unsigned* __restrict__ zr8,
        const float* __restrict__ nf, const unsigned* __restrict__ pack,
        const int* __restrict__ S, float4* __restrict__ out4,
        float scale, int N, int C, int npart, int nbuck, int obits, int twoE) {
    __shared__ int adjl[CAP];
    __shared__ int lcnt[RANGE];
    __shared__ int lexc[RANGE];
    __shared__ int ldeg[RANGE];
    __shared__ int sbuf[RANGE];

    int b = blockIdx.x;
    int bstart = S[b * npart];
    int bend   = (b + 1 < nbuck) ? S[(b + 1) * npart] : twoE;
    int bsize  = bend - bstart;
    int tid = threadIdx.x;
    unsigned omask = (1u << obits) - 1u;
    int node0 = b << RANGE_SHIFT;

    if (bsize <= CAP) {
        if (tid < RANGE) lcnt[tid] = 0;
        __syncthreads();
        // Pass A: hist of node-locals over own region.
        for (int it = bstart + tid; it < bend; it += 256)
            atomicAdd(&lcnt[pack[it] >> obits], 1);
        __syncthreads();
        // Exclusive scan of 64 counters (Hillis-Steele in LDS).
        if (tid < RANGE) sbuf[tid] = lcnt[tid];
        __syncthreads();
        for (int off = 1; off < RANGE; off <<= 1) {
            int v = 0, u = 0;
            if (tid < RANGE) { v = sbuf[tid]; if (tid >= off) u = sbuf[tid - off]; }
            __syncthreads();
            if (tid < RANGE) sbuf[tid] = v + u;
            __syncthreads();
        }
        if (tid < RANGE) {
            int inc = sbuf[tid], d = lcnt[tid];
            lexc[tid] = inc - d;
            ldeg[tid] = d;
            lcnt[tid] = 0;               // reuse as bump
        }
        __syncthreads();
        // Pass B: place into per-node adjacency (L2-hot re-read).
        for (int it = bstart + tid; it < bend; it += 256) {
            unsigned pk = pack[it];
            int il = (int)(pk >> obits);
            int r = atomicAdd(&lcnt[il], 1);
            adjl[lexc[il] + r] = (int)(pk & omask);
        }
        __syncthreads();
        // Pass C: register gather + fused finalize. RANGE*C tasks.
        for (int task = tid; task < RANGE * 12; task += 256) {
            int nl = task / 12;
            int c  = task - nl * 12;
            int node = node0 + nl;
            if (node >= N) continue;
            int s  = lexc[nl];
            int dg = ldeg[nl];
            float4 sum = make_float4(0.f, 0.f, 0.f, 0.f);
            #pragma unroll 4
            for (int k = 0; k < dg; ++k) {
                int j = adjl[s + k];
                float4 v = fp8x4_to_f32(zr8[(long)j * C + c]);
                sum.x += v.x; sum.y += v.y; sum.z += v.z; sum.w += v.w;
            }
            float nfi = nf[node];
            float4 zi = z4[(long)node * C + c];
            float a   = scale * nfi;
            float dn  = (float)dg * nfi;
            float4 o;
            o.x = zi.x - a * (dn * zi.x - sum.x);
            o.y = zi.y - a * (dn * zi.y - sum.y);
            o.z = zi.z - a * (dn * zi.z - sum.z);
            o.w = zi.w - a * (dn * zi.w - sum.w);
            out4[(long)node * C + c] = o;
        }
    } else {
        // Slow correct path (bucket > CAP; +11 sigma, never expected).
        for (int task = tid; task < RANGE * 12; task += 256) {
            int nl = task / 12;
            int c  = task - nl * 12;
            int node = node0 + nl;
            if (node >= N) continue;
            float4 sum = make_float4(0.f, 0.f, 0.f, 0.f);
            int dg = 0;
            for (int it = bstart; it < bend; ++it) {
                unsigned pk = pack[it];
                if ((int)(pk >> obits) == nl) {
                    ++dg;
                    float4 v = fp8x4_to_f32(zr8[(long)(pk & omask) * C + c]);
                    sum.x += v.x; sum.y += v.y; sum.z += v.z; sum.w += v.w;
                }
            }
            float nfi = nf[node];
            float4 zi = z4[(long)node * C + c];
            float a   = scale * nfi;
            float dn  = (float)dg * nfi;
            float4 o;
            o.x = zi.x - a * (dn * zi.x - sum.x);
            o.y = zi.y - a * (dn * zi.y - sum.y);
            o.z = zi.z - a * (dn * zi.z - sum.z);
            o.w = zi.w - a * (dn * zi.w - sum.w);
            out4[(long)node * C + c] = o;
        }
    }
}

// ---- fallback (round-1 atomic path) ----
__global__ void edge_scatter_kernel(const float* __restrict__ z, const int* __restrict__ ei,
                                    const float* __restrict__ nf, float* __restrict__ acc,
                                    int E, int D, long total) {
    long idx = (long)blockIdx.x * blockDim.x + threadIdx.x;
    if (idx >= total) return;
    int e = (int)(idx / D);
    int d = (int)(idx - (long)e * D);
    int r = ei[e];
    int c = ei[E + e];
    float diff = nf[r] * z[(long)r * D + d] - nf[c] * z[(long)c * D + d];
    atomicAdd(&acc[(long)r * D + d],  diff);
    atomicAdd(&acc[(long)c * D + d], -diff);
}
__global__ void finalize_kernel(const float* __restrict__ z, const float* __restrict__ nf,
                                float* __restrict__ out, float scale, int D, long total) {
    long i = (long)blockIdx.x * blockDim.x + threadIdx.x;
    if (i >= total) return;
    int node = (int)(i / D);
    out[i] = z[i] - scale * nf[node] * out[i];
}

extern "C" void kernel_launch(void* const* d_in, const int* in_sizes, int n_in,
                              void* d_out, int out_size, void* d_ws, size_t ws_size,
                              hipStream_t stream) {
    const float* z  = (const float*)d_in[0];
    const int*   ei = (const int*)d_in[2];
    const float* nf = (const float*)d_in[3];
    float* out = (float*)d_out;

    const int ND = in_sizes[0];
    const int Nn = in_sizes[3];
    const int D  = ND / Nn;
    const int E  = in_sizes[2] / 2;
    const int twoE = 2 * E;
    const float scale = 0.1f * 2.0f / (float)Nn;
    const int block = 256;

    int obits = 1;
    while ((1 << obits) < Nn) obits++;
    const int nbuck = (Nn + RANGE - 1) >> RANGE_SHIFT;   // 1563
    const int npart = (twoE + IPB - 1) / IPB;            // 782
    const long M = (long)nbuck * npart;                  // ~1.22M
    const int NBscan = (int)((M + SCAN_CHUNK - 1) / SCAN_CHUNK);  // ~597

    auto align_up = [](size_t x) { return (x + 255) & ~(size_t)255; };
    size_t off_counts = 0;
    size_t off_S      = off_counts + align_up((size_t)M * 4);
    size_t off_bsum   = off_S      + align_up((size_t)M * 4);
    size_t off_boff   = off_bsum   + align_up((size_t)NBscan * 4);
    size_t off_pack   = off_boff   + align_up((size_t)NBscan * 4);
    size_t off_zr8    = off_pack   + align_up((size_t)twoE * 4);
    size_t need       = off_zr8    + align_up((size_t)ND);

    bool ok = (D == 48) && (nbuck <= MAX_BUCKETS) && (obits + RANGE_SHIFT <= 32) &&
              (NBscan <= 1024) && (ws_size >= need);

    if (!ok) {
        hipMemsetAsync(out, 0, (size_t)ND * sizeof(float), stream);
        const long totalE = (long)E * D;
        edge_scatter_kernel<<<(int)((totalE + block - 1) / block), block, 0, stream>>>(
            z, ei, nf, out, E, D, totalE);
        finalize_kernel<<<(ND + block - 1) / block, block, 0, stream>>>(
            z, nf, out, scale, D, (long)ND);
        return;
    }

    char* w = (char*)d_ws;
    int*      counts = (int*)(w + off_counts);
    int*      S      = (int*)(w + off_S);
    int*      bsum   = (int*)(w + off_bsum);
    int*      boff   = (int*)(w + off_boff);
    unsigned* pack   = (unsigned*)(w + off_pack);
    uchar4*   zr8    = (uchar4*)(w + off_zr8);

    const int C = D / 4;                 // 12
    long totalP = (long)Nn * C;

    count_kernel<<<npart, block, 0, stream>>>(ei, counts, twoE, npart, nbuck,
                                              (const float4*)z, nf, zr8, C, totalP);
    scan_block_sums<<<NBscan, 256, 0, stream>>>(counts, bsum, (int)M);
    scan_bsums<<<1, 256, 0, stream>>>(bsum, boff, NBscan);
    scan_chunks<<<NBscan, 256, 0, stream>>>(counts, boff, S, (int)M);
    partition_kernel<<<npart, block, 0, stream>>>(ei, S, pack, E, npart, nbuck, obits);
    bucket_sort_gather<<<nbuck, block, 0, stream>>>(
        (const float4*)z, (const unsigned*)zr8, nf, pack, S, (float4*)out,
        scale, Nn, C, npart, nbuck, obits, twoE);
}

// Round 11
// 106.534 us; speedup vs baseline: 1.2786x; 1.2786x over previous
//
#include <hip/hip_runtime.h>
#include <hip/hip_fp8.h>

// out[i] = z[i] - COEFF*(2/N)*nf[i]*g[i],  g[i] = deg(i)*zr[i] - sum_{adj} zr[j],
// zr[j] = nf[j]*z[j].  adj counts both edge directions.
//
// Pipeline (no global atomics):
//  1) count (+fused fp8 zr precompute): per-block LDS hist of node>>7
//  2) scan:      exclusive scan -> S (deterministic bucket bases)
//  3) partition: pack (il<<obits | other) into 128-node bucket regions (LDS bump)
//  4) bucket_sort_gather: block per 128-node bucket; hist -> scan -> place into
//     LDS adjl, then register fp8 gather + fused finalize.
//
// Geometry (r9/r10 lessons): RANGE=128 + IPB=8192 keeps partition runs long
// (IPB/nbuck ~ 10.5 records -> coalesced pack writes; r10's RANGE=64 gave 2.6
// -> 98MB write-allocate). Gather TLP fixed with 512-thread blocks instead
// (782 blocks x 8 waves, ~24 waves/CU vs r9's 12 at 26% occupancy).

#define RANGE_SHIFT 7
#define RANGE 128
#define IPB 8192
#define SCAN_CHUNK 2048
#define MAX_BUCKETS 1024
#define CAP 4608
#define BLK 512

typedef float f32x2 __attribute__((ext_vector_type(2)));

static __device__ __forceinline__ unsigned char f2fp8(float f) {
    __hip_fp8_e4m3 h(f);
    return (unsigned char)h.__x;
}
static __device__ __forceinline__ float fp82f_sw(unsigned char b) {
    __hip_fp8_e4m3 h; h.__x = (__hip_fp8_storage_t)b; return (float)h;
}
static __device__ __forceinline__ float4 fp8x4_to_f32(unsigned v) {
#if __has_builtin(__builtin_amdgcn_cvt_pk_f32_fp8)
    f32x2 lo = __builtin_amdgcn_cvt_pk_f32_fp8(v, false);
    f32x2 hi = __builtin_amdgcn_cvt_pk_f32_fp8(v, true);
    return make_float4(lo[0], lo[1], hi[0], hi[1]);
#else
    return make_float4(fp82f_sw((unsigned char)(v & 0xFF)),
                       fp82f_sw((unsigned char)((v >> 8) & 0xFF)),
                       fp82f_sw((unsigned char)((v >> 16) & 0xFF)),
                       fp82f_sw((unsigned char)(v >> 24)));
#endif
}

// count + fused zr8 precompute (independent work, hides under hist latency)
__global__ __launch_bounds__(BLK) void count_kernel(const int* __restrict__ ei,
        int* __restrict__ counts, int twoE, int npart, int nbuck,
        const float4* __restrict__ z4, const float* __restrict__ nf,
        uchar4* __restrict__ zr8, int C, long totalP) {
    __shared__ int lcnt[MAX_BUCKETS];
    for (int k = threadIdx.x; k < nbuck; k += BLK) lcnt[k] = 0;
    __syncthreads();
    // fused precompute slice (grid-stride over npart blocks)
    for (long t = (long)blockIdx.x * BLK + threadIdx.x; t < totalP;
         t += (long)npart * BLK) {
        int node = (int)(t / C);
        float s = nf[node];
        float4 v = z4[t];
        uchar4 q;
        q.x = f2fp8(s * v.x); q.y = f2fp8(s * v.y);
        q.z = f2fp8(s * v.z); q.w = f2fp8(s * v.w);
        zr8[t] = q;
    }
    int base = blockIdx.x * IPB;
    int endt = min(base + IPB, twoE);
    for (int t = base + threadIdx.x; t < endt; t += BLK)
        atomicAdd(&lcnt[ei[t] >> RANGE_SHIFT], 1);
    __syncthreads();
    for (int k = threadIdx.x; k < nbuck; k += BLK)
        counts[k * npart + blockIdx.x] = lcnt[k];
}

__global__ __launch_bounds__(256) void scan_block_sums(const int* __restrict__ deg,
                                                       int* __restrict__ bsum, int N) {
    __shared__ int lds[256];
    int base = blockIdx.x * SCAN_CHUNK;
    int s = 0;
    #pragma unroll
    for (int k = 0; k < 8; ++k) {
        int i = base + k * 256 + threadIdx.x;
        if (i < N) s += deg[i];
    }
    lds[threadIdx.x] = s;
    __syncthreads();
    for (int off = 128; off > 0; off >>= 1) {
        if (threadIdx.x < off) lds[threadIdx.x] += lds[threadIdx.x + off];
        __syncthreads();
    }
    if (threadIdx.x == 0) bsum[blockIdx.x] = lds[0];
}

__global__ void scan_bsums(const int* __restrict__ bsum, int* __restrict__ boff, int NB) {
    __shared__ int lds[1024];
    for (int i = threadIdx.x; i < 1024; i += blockDim.x) lds[i] = (i < NB) ? bsum[i] : 0;
    __syncthreads();
    if (threadIdx.x == 0) {
        int run = 0;
        for (int i = 0; i < NB; ++i) { int v = lds[i]; lds[i] = run; run += v; }
    }
    __syncthreads();
    for (int i = threadIdx.x; i < NB; i += blockDim.x) boff[i] = lds[i];
}

__global__ __launch_bounds__(256) void scan_chunks(const int* __restrict__ deg,
                                                   const int* __restrict__ boff,
                                                   int* __restrict__ starts, int N) {
    __shared__ int buf[SCAN_CHUNK];
    __shared__ int tsum[256];
    int base = blockIdx.x * SCAN_CHUNK;
    #pragma unroll
    for (int k = 0; k < 8; ++k) {
        int i = base + k * 256 + threadIdx.x;
        buf[k * 256 + threadIdx.x] = (i < N) ? deg[i] : 0;
    }
    __syncthreads();
    int lo = threadIdx.x * 8;
    int s = 0;
    #pragma unroll
    for (int k = 0; k < 8; ++k) s += buf[lo + k];
    tsum[threadIdx.x] = s;
    __syncthreads();
    for (int off = 1; off < 256; off <<= 1) {
        int a = tsum[threadIdx.x];
        int b = (threadIdx.x >= (unsigned)off) ? tsum[threadIdx.x - off] : 0;
        __syncthreads();
        tsum[threadIdx.x] = a + b;
        __syncthreads();
    }
    int run = boff[blockIdx.x] + (tsum[threadIdx.x] - s);
    #pragma unroll
    for (int k = 0; k < 8; ++k) {
        int i = base + lo + k;
        if (i < N) starts[i] = run;
        run += buf[lo + k];
    }
}

__global__ __launch_bounds__(BLK) void partition_kernel(const int* __restrict__ ei,
        const int* __restrict__ S, unsigned* __restrict__ pack,
        int E, int npart, int nbuck, int obits) {
    __shared__ int lbase[MAX_BUCKETS];
    for (int k = threadIdx.x; k < nbuck; k += BLK)
        lbase[k] = S[k * npart + blockIdx.x];
    __syncthreads();
    int twoE = 2 * E;
    int base = blockIdx.x * IPB;
    int endt = min(base + IPB, twoE);
    for (int t = base + threadIdx.x; t < endt; t += BLK) {
        int node  = ei[t];
        int other = (t < E) ? ei[t + E] : ei[t - E];
        int pos = atomicAdd(&lbase[node >> RANGE_SHIFT], 1);
        pack[pos] = ((unsigned)(node & (RANGE - 1)) << obits) | (unsigned)other;
    }
}

// Fused: in-LDS counting sort of own bucket region + fp8 register gather + finalize.
__global__ __launch_bounds__(BLK) void bucket_sort_gather(
        const float4* __restrict__ z4, const unsigned* __restrict__ zr8,
        const float* __restrict__ nf, const unsigned* __restrict__ pack,
        const int* __restrict__ S, float4* __restrict__ out4,
        float scale, int N, int C, int npart, int nbuck, int obits, int twoE) {
    __shared__ int adjl[CAP];
    __shared__ int lcnt[RANGE];
    __shared__ int lexc[RANGE];
    __shared__ int ldeg[RANGE];
    __shared__ int sbuf[RANGE];

    int b = blockIdx.x;
    int bstart = S[b * npart];
    int bend   = (b + 1 < nbuck) ? S[(b + 1) * npart] : twoE;
    int bsize  = bend - bstart;
    int tid = threadIdx.x;
    unsigned omask = (1u << obits) - 1u;
    int node0 = b << RANGE_SHIFT;

    if (bsize <= CAP) {
        if (tid < RANGE) lcnt[tid] = 0;
        __syncthreads();
        // Pass A: hist of node-locals over own region.
        for (int it = bstart + tid; it < bend; it += BLK)
            atomicAdd(&lcnt[pack[it] >> obits], 1);
        __syncthreads();
        // Exclusive scan of 128 counters (Hillis-Steele, barriers outside guards).
        if (tid < RANGE) sbuf[tid] = lcnt[tid];
        __syncthreads();
        for (int off = 1; off < RANGE; off <<= 1) {
            int v = 0, u = 0;
            if (tid < RANGE) { v = sbuf[tid]; if (tid >= off) u = sbuf[tid - off]; }
            __syncthreads();
            if (tid < RANGE) sbuf[tid] = v + u;
            __syncthreads();
        }
        if (tid < RANGE) {
            int inc = sbuf[tid], d = lcnt[tid];
            lexc[tid] = inc - d;
            ldeg[tid] = d;
            lcnt[tid] = 0;               // reuse as bump
        }
        __syncthreads();
        // Pass B: place into per-node adjacency (L2-hot re-read).
        for (int it = bstart + tid; it < bend; it += BLK) {
            unsigned pk = pack[it];
            int il = (int)(pk >> obits);
            int r = atomicAdd(&lcnt[il], 1);
            adjl[lexc[il] + r] = (int)(pk & omask);
        }
        __syncthreads();
        // Pass C: register gather + fused finalize. RANGE*12 = 1536 tasks.
        for (int task = tid; task < RANGE * 12; task += BLK) {
            int nl = task / 12;
            int c  = task - nl * 12;
            int node = node0 + nl;
            if (node >= N) continue;
            int s  = lexc[nl];
            int dg = ldeg[nl];
            float4 sum = make_float4(0.f, 0.f, 0.f, 0.f);
            #pragma unroll 4
            for (int k = 0; k < dg; ++k) {
                int j = adjl[s + k];
                float4 v = fp8x4_to_f32(zr8[(long)j * C + c]);
                sum.x += v.x; sum.y += v.y; sum.z += v.z; sum.w += v.w;
            }
            float nfi = nf[node];
            float4 zi = z4[(long)node * C + c];
            float a   = scale * nfi;
            float dn  = (float)dg * nfi;
            float4 o;
            o.x = zi.x - a * (dn * zi.x - sum.x);
            o.y = zi.y - a * (dn * zi.y - sum.y);
            o.z = zi.z - a * (dn * zi.z - sum.z);
            o.w = zi.w - a * (dn * zi.w - sum.w);
            out4[(long)node * C + c] = o;
        }
    } else {
        // Slow correct path (bucket > CAP; +8 sigma, never expected).
        for (int task = tid; task < RANGE * 12; task += BLK) {
            int nl = task / 12;
            int c  = task - nl * 12;
            int node = node0 + nl;
            if (node >= N) continue;
            float4 sum = make_float4(0.f, 0.f, 0.f, 0.f);
            int dg = 0;
            for (int it = bstart; it < bend; ++it) {
                unsigned pk = pack[it];
                if ((int)(pk >> obits) == nl) {
                    ++dg;
                    float4 v = fp8x4_to_f32(zr8[(long)(pk & omask) * C + c]);
                    sum.x += v.x; sum.y += v.y; sum.z += v.z; sum.w += v.w;
                }
            }
            float nfi = nf[node];
            float4 zi = z4[(long)node * C + c];
            float a   = scale * nfi;
            float dn  = (float)dg * nfi;
            float4 o;
            o.x = zi.x - a * (dn * zi.x - sum.x);
            o.y = zi.y - a * (dn * zi.y - sum.y);
            o.z = zi.z - a * (dn * zi.z - sum.z);
            o.w = zi.w - a * (dn * zi.w - sum.w);
            out4[(long)node * C + c] = o;
        }
    }
}

// ---- fallback (round-1 atomic path) ----
__global__ void edge_scatter_kernel(const float* __restrict__ z, const int* __restrict__ ei,
                                    const float* __restrict__ nf, float* __restrict__ acc,
                                    int E, int D, long total) {
    long idx = (long)blockIdx.x * blockDim.x + threadIdx.x;
    if (idx >= total) return;
    int e = (int)(idx / D);
    int d = (int)(idx - (long)e * D);
    int r = ei[e];
    int c = ei[E + e];
    float diff = nf[r] * z[(long)r * D + d] - nf[c] * z[(long)c * D + d];
    atomicAdd(&acc[(long)r * D + d],  diff);
    atomicAdd(&acc[(long)c * D + d], -diff);
}
__global__ void finalize_kernel(const float* __restrict__ z, const float* __restrict__ nf,
                                float* __restrict__ out, float scale, int D, long total) {
    long i = (long)blockIdx.x * blockDim.x + threadIdx.x;
    if (i >= total) return;
    int node = (int)(i / D);
    out[i] = z[i] - scale * nf[node] * out[i];
}

extern "C" void kernel_launch(void* const* d_in, const int* in_sizes, int n_in,
                              void* d_out, int out_size, void* d_ws, size_t ws_size,
                              hipStream_t stream) {
    const float* z  = (const float*)d_in[0];
    const int*   ei = (const int*)d_in[2];
    const float* nf = (const float*)d_in[3];
    float* out = (float*)d_out;

    const int ND = in_sizes[0];
    const int Nn = in_sizes[3];
    const int D  = ND / Nn;
    const int E  = in_sizes[2] / 2;
    const int twoE = 2 * E;
    const float scale = 0.1f * 2.0f / (float)Nn;

    int obits = 1;
    while ((1 << obits) < Nn) obits++;
    const int nbuck = (Nn + RANGE - 1) >> RANGE_SHIFT;   // 782
    const int npart = (twoE + IPB - 1) / IPB;            // 391
    const long M = (long)nbuck * npart;                  // ~306K
    const int NBscan = (int)((M + SCAN_CHUNK - 1) / SCAN_CHUNK);  // ~150

    auto align_up = [](size_t x) { return (x + 255) & ~(size_t)255; };
    size_t off_counts = 0;
    size_t off_S      = off_counts + align_up((size_t)M * 4);
    size_t off_bsum   = off_S      + align_up((size_t)M * 4);
    size_t off_boff   = off_bsum   + align_up((size_t)NBscan * 4);
    size_t off_pack   = off_boff   + align_up((size_t)NBscan * 4);
    size_t off_zr8    = off_pack   + align_up((size_t)twoE * 4);
    size_t need       = off_zr8    + align_up((size_t)ND);

    bool ok = (D == 48) && (nbuck <= MAX_BUCKETS) && (obits + RANGE_SHIFT <= 32) &&
              (NBscan <= 1024) && (ws_size >= need);

    if (!ok) {
        hipMemsetAsync(out, 0, (size_t)ND * sizeof(float), stream);
        const long totalE = (long)E * D;
        edge_scatter_kernel<<<(int)((totalE + 255) / 256), 256, 0, stream>>>(
            z, ei, nf, out, E, D, totalE);
        finalize_kernel<<<(ND + 255) / 256, 256, 0, stream>>>(
            z, nf, out, scale, D, (long)ND);
        return;
    }

    char* w = (char*)d_ws;
    int*      counts = (int*)(w + off_counts);
    int*      S      = (int*)(w + off_S);
    int*      bsum   = (int*)(w + off_bsum);
    int*      boff   = (int*)(w + off_boff);
    unsigned* pack   = (unsigned*)(w + off_pack);
    uchar4*   zr8    = (uchar4*)(w + off_zr8);

    const int C = D / 4;                 // 12
    long totalP = (long)Nn * C;

    count_kernel<<<npart, BLK, 0, stream>>>(ei, counts, twoE, npart, nbuck,
                                            (const float4*)z, nf, zr8, C, totalP);
    scan_block_sums<<<NBscan, 256, 0, stream>>>(counts, bsum, (int)M);
    scan_bsums<<<1, 256, 0, stream>>>(bsum, boff, NBscan);
    scan_chunks<<<NBscan, 256, 0, stream>>>(counts, boff, S, (int)M);
    partition_kernel<<<npart, BLK, 0, stream>>>(ei, S, pack, E, npart, nbuck, obits);
    bucket_sort_gather<<<nbuck, BLK, 0, stream>>>(
        (const float4*)z, (const unsigned*)zr8, nf, pack, S, (float4*)out,
        scale, Nn, C, npart, nbuck, obits, twoE);
}

// Round 12
// 100.044 us; speedup vs baseline: 1.3615x; 1.0649x over previous
//
#include <hip/hip_runtime.h>
#include <hip/hip_fp8.h>

// out[i] = z[i] - COEFF*(2/N)*nf[i]*g[i],  g[i] = deg(i)*zr[i] - sum_{adj} zr[j],
// zr[j] = nf[j]*z[j].  adj counts both edge directions.
//
// 3-kernel pipeline (count/scan subsystem deleted; fixed-stride bucket regions):
//  0) memset gfill (782 ints)
//  1) partition2 (+fused fp8 zr precompute): per-block LDS hist of node>>7,
//     ONE global atomicAdd per (block,bucket) reserves a run in the bucket's
//     fixed region pack[b*CAP ..], then coalesced run writes (LDS bump).
//  2) bucket_sort_gather: block per 128-node bucket; LDS counting sort of its
//     region -> per-node adjacency, register fp8 gather + fused finalize.
//
// CAP = 4608 = mean bucket (4092) + 8 sigma(64): overflow effectively
// impossible; guarded by clamp. Within-bucket record order is atomic-order
// dependent -> per-node f32 sum order varies ~1e-6 (<< 0.101 threshold).

#define RANGE_SHIFT 7
#define RANGE 128
#define IPB 8192
#define MAX_BUCKETS 1024
#define CAP 4608
#define BLK 512

typedef float f32x2 __attribute__((ext_vector_type(2)));

static __device__ __forceinline__ unsigned char f2fp8(float f) {
    __hip_fp8_e4m3 h(f);
    return (unsigned char)h.__x;
}
static __device__ __forceinline__ float fp82f_sw(unsigned char b) {
    __hip_fp8_e4m3 h; h.__x = (__hip_fp8_storage_t)b; return (float)h;
}
static __device__ __forceinline__ float4 fp8x4_to_f32(unsigned v) {
#if __has_builtin(__builtin_amdgcn_cvt_pk_f32_fp8)
    f32x2 lo = __builtin_amdgcn_cvt_pk_f32_fp8(v, false);
    f32x2 hi = __builtin_amdgcn_cvt_pk_f32_fp8(v, true);
    return make_float4(lo[0], lo[1], hi[0], hi[1]);
#else
    return make_float4(fp82f_sw((unsigned char)(v & 0xFF)),
                       fp82f_sw((unsigned char)((v >> 8) & 0xFF)),
                       fp82f_sw((unsigned char)((v >> 16) & 0xFF)),
                       fp82f_sw((unsigned char)(v >> 24)));
#endif
}

// partition + fused zr8 precompute. One kernel replaces count+3 scans+partition.
__global__ __launch_bounds__(BLK) void partition2_kernel(const int* __restrict__ ei,
        int* __restrict__ gfill, unsigned* __restrict__ pack,
        int E, int npart, int nbuck, int obits,
        const float4* __restrict__ z4, const float* __restrict__ nf,
        uchar4* __restrict__ zr8, int C, long totalP) {
    __shared__ int lcnt[MAX_BUCKETS];   // pass1 hist, then bump counter
    __shared__ int lbase[MAX_BUCKETS];  // reserved global run base
    for (int k = threadIdx.x; k < nbuck; k += BLK) lcnt[k] = 0;
    __syncthreads();

    // fused precompute slice (independent; hides under hist latency)
    for (long t = (long)blockIdx.x * BLK + threadIdx.x; t < totalP;
         t += (long)npart * BLK) {
        int node = (int)(t / C);
        float s = nf[node];
        float4 v = z4[t];
        uchar4 q;
        q.x = f2fp8(s * v.x); q.y = f2fp8(s * v.y);
        q.z = f2fp8(s * v.z); q.w = f2fp8(s * v.w);
        zr8[t] = q;
    }

    int twoE = 2 * E;
    int base = blockIdx.x * IPB;
    int endt = min(base + IPB, twoE);

    // Pass 1: LDS hist of own records (node column; L2-resident for pass 2).
    for (int t = base + threadIdx.x; t < endt; t += BLK)
        atomicAdd(&lcnt[ei[t] >> RANGE_SHIFT], 1);
    __syncthreads();

    // Reserve one run per non-empty bucket (coalesced global atomics).
    for (int k = threadIdx.x; k < nbuck; k += BLK) {
        int c = lcnt[k];
        lbase[k] = (c > 0) ? atomicAdd(&gfill[k], c) : 0;
        lcnt[k] = 0;                      // reuse as bump
    }
    __syncthreads();

    // Pass 2: place records into the reserved runs (coalesced ~10-rec runs).
    for (int t = base + threadIdx.x; t < endt; t += BLK) {
        int node  = ei[t];
        int other = (t < E) ? ei[t + E] : ei[t - E];
        int bk = node >> RANGE_SHIFT;
        int pos = lbase[bk] + atomicAdd(&lcnt[bk], 1);
        if (pos < CAP)                    // 8-sigma guard (never expected)
            pack[(long)bk * CAP + pos] =
                ((unsigned)(node & (RANGE - 1)) << obits) | (unsigned)other;
    }
}

// Fused: in-LDS counting sort of own bucket region + fp8 register gather + finalize.
__global__ __launch_bounds__(BLK) void bucket_sort_gather(
        const float4* __restrict__ z4, const unsigned* __restrict__ zr8,
        const float* __restrict__ nf, const unsigned* __restrict__ pack,
        const int* __restrict__ gfill, float4* __restrict__ out4,
        float scale, int N, int C, int nbuck, int obits) {
    __shared__ int adjl[CAP];
    __shared__ int lcnt[RANGE];
    __shared__ int lexc[RANGE];
    __shared__ int ldeg[RANGE];
    __shared__ int sbuf[RANGE];

    int b = blockIdx.x;
    long bstart = (long)b * CAP;
    int bsize = gfill[b];
    if (bsize > CAP) bsize = CAP;
    int tid = threadIdx.x;
    unsigned omask = (1u << obits) - 1u;
    int node0 = b << RANGE_SHIFT;

    if (tid < RANGE) lcnt[tid] = 0;
    __syncthreads();
    // Pass A: hist of node-locals over own region.
    for (int it = tid; it < bsize; it += BLK)
        atomicAdd(&lcnt[pack[bstart + it] >> obits], 1);
    __syncthreads();
    // Exclusive scan of 128 counters (Hillis-Steele, barriers outside guards).
    if (tid < RANGE) sbuf[tid] = lcnt[tid];
    __syncthreads();
    for (int off = 1; off < RANGE; off <<= 1) {
        int v = 0, u = 0;
        if (tid < RANGE) { v = sbuf[tid]; if (tid >= off) u = sbuf[tid - off]; }
        __syncthreads();
        if (tid < RANGE) sbuf[tid] = v + u;
        __syncthreads();
    }
    if (tid < RANGE) {
        int inc = sbuf[tid], d = lcnt[tid];
        lexc[tid] = inc - d;
        ldeg[tid] = d;
        lcnt[tid] = 0;                    // reuse as bump
    }
    __syncthreads();
    // Pass B: place into per-node adjacency (L2-hot re-read).
    for (int it = tid; it < bsize; it += BLK) {
        unsigned pk = pack[bstart + it];
        int il = (int)(pk >> obits);
        int r = atomicAdd(&lcnt[il], 1);
        adjl[lexc[il] + r] = (int)(pk & omask);
    }
    __syncthreads();
    // Pass C: register gather + fused finalize. RANGE*12 = 1536 tasks.
    for (int task = tid; task < RANGE * 12; task += BLK) {
        int nl = task / 12;
        int c  = task - nl * 12;
        int node = node0 + nl;
        if (node >= N) continue;
        int s  = lexc[nl];
        int dg = ldeg[nl];
        float4 sum = make_float4(0.f, 0.f, 0.f, 0.f);
        #pragma unroll 4
        for (int k = 0; k < dg; ++k) {
            int j = adjl[s + k];
            float4 v = fp8x4_to_f32(zr8[(long)j * C + c]);
            sum.x += v.x; sum.y += v.y; sum.z += v.z; sum.w += v.w;
        }
        float nfi = nf[node];
        float4 zi = z4[(long)node * C + c];
        float a   = scale * nfi;
        float dn  = (float)dg * nfi;
        float4 o;
        o.x = zi.x - a * (dn * zi.x - sum.x);
        o.y = zi.y - a * (dn * zi.y - sum.y);
        o.z = zi.z - a * (dn * zi.z - sum.z);
        o.w = zi.w - a * (dn * zi.w - sum.w);
        out4[(long)node * C + c] = o;
    }
}

// ---- fallback (round-1 atomic path) ----
__global__ void edge_scatter_kernel(const float* __restrict__ z, const int* __restrict__ ei,
                                    const float* __restrict__ nf, float* __restrict__ acc,
                                    int E, int D, long total) {
    long idx = (long)blockIdx.x * blockDim.x + threadIdx.x;
    if (idx >= total) return;
    int e = (int)(idx / D);
    int d = (int)(idx - (long)e * D);
    int r = ei[e];
    int c = ei[E + e];
    float diff = nf[r] * z[(long)r * D + d] - nf[c] * z[(long)c * D + d];
    atomicAdd(&acc[(long)r * D + d],  diff);
    atomicAdd(&acc[(long)c * D + d], -diff);
}
__global__ void finalize_kernel(const float* __restrict__ z, const float* __restrict__ nf,
                                float* __restrict__ out, float scale, int D, long total) {
    long i = (long)blockIdx.x * blockDim.x + threadIdx.x;
    if (i >= total) return;
    int node = (int)(i / D);
    out[i] = z[i] - scale * nf[node] * out[i];
}

extern "C" void kernel_launch(void* const* d_in, const int* in_sizes, int n_in,
                              void* d_out, int out_size, void* d_ws, size_t ws_size,
                              hipStream_t stream) {
    const float* z  = (const float*)d_in[0];
    const int*   ei = (const int*)d_in[2];
    const float* nf = (const float*)d_in[3];
    float* out = (float*)d_out;

    const int ND = in_sizes[0];
    const int Nn = in_sizes[3];
    const int D  = ND / Nn;
    const int E  = in_sizes[2] / 2;
    const int twoE = 2 * E;
    const float scale = 0.1f * 2.0f / (float)Nn;

    int obits = 1;
    while ((1 << obits) < Nn) obits++;
    const int nbuck = (Nn + RANGE - 1) >> RANGE_SHIFT;   // 782
    const int npart = (twoE + IPB - 1) / IPB;            // 391

    auto align_up = [](size_t x) { return (x + 255) & ~(size_t)255; };
    size_t off_gfill = 0;
    size_t off_pack  = off_gfill + align_up((size_t)nbuck * 4);
    size_t off_zr8   = off_pack  + align_up((size_t)nbuck * CAP * 4);
    size_t need      = off_zr8   + align_up((size_t)ND);

    // mean bucket size must leave >= ~8 sigma headroom under CAP
    bool ok = (D == 48) && (nbuck <= MAX_BUCKETS) && (obits + RANGE_SHIFT <= 32) &&
              (twoE / nbuck <= CAP - 512) && (ws_size >= need);

    if (!ok) {
        hipMemsetAsync(out, 0, (size_t)ND * sizeof(float), stream);
        const long totalE = (long)E * D;
        edge_scatter_kernel<<<(int)((totalE + 255) / 256), 256, 0, stream>>>(
            z, ei, nf, out, E, D, totalE);
        finalize_kernel<<<(ND + 255) / 256, 256, 0, stream>>>(
            z, nf, out, scale, D, (long)ND);
        return;
    }

    char* w = (char*)d_ws;
    int*      gfill = (int*)(w + off_gfill);
    unsigned* pack  = (unsigned*)(w + off_pack);
    uchar4*   zr8   = (uchar4*)(w + off_zr8);

    const int C = D / 4;                 // 12
    long totalP = (long)Nn * C;

    hipMemsetAsync(gfill, 0, (size_t)nbuck * 4, stream);
    partition2_kernel<<<npart, BLK, 0, stream>>>(ei, gfill, pack, E, npart, nbuck,
                                                 obits, (const float4*)z, nf, zr8, C, totalP);
    bucket_sort_gather<<<nbuck, BLK, 0, stream>>>(
        (const float4*)z, (const unsigned*)zr8, nf, pack, gfill, (float4*)out,
        scale, Nn, C, nbuck, obits);
}

// Round 13
// 92.847 us; speedup vs baseline: 1.4671x; 1.0775x over previous
//
#include <hip/hip_runtime.h>
#include <hip/hip_fp8.h>

// out[i] = z[i] - COEFF*(2/N)*nf[i]*g[i],  g[i] = deg(i)*zr[i] - sum_{adj} zr[j],
// zr[j] = nf[j]*z[j].  adj counts both edge directions.
//
// 3-dispatch pipeline (fixed-stride bucket regions, no count/scan):
//  0) memset gfill (391 ints)
//  1) partition2 (+fused fp8 zr precompute): per-block LDS hist of node>>8,
//     ONE global atomicAdd per (block,bucket) reserves a run in the bucket's
//     fixed region pack[b*CAP ..], then run writes (LDS bump).
//     256-node buckets -> runs ~21 records (84B): halves r12's write-allocate
//     traffic (76MB WRITE was the partition bottleneck).
//  2) bucket_sort_gather (1024 thr): block per 256-node bucket; LDS counting
//     sort of its region -> per-node adjacency, register fp8 gather + finalize.
//     391 blocks x 16 waves = same total waves as r11's best gather.

#define RANGE_SHIFT 8
#define RANGE 256
#define IPB 8192
#define MAX_BUCKETS 512
#define CAP 9216
#define BLK 512
#define GBLK 1024

typedef float f32x2 __attribute__((ext_vector_type(2)));

static __device__ __forceinline__ unsigned char f2fp8(float f) {
    __hip_fp8_e4m3 h(f);
    return (unsigned char)h.__x;
}
static __device__ __forceinline__ float fp82f_sw(unsigned char b) {
    __hip_fp8_e4m3 h; h.__x = (__hip_fp8_storage_t)b; return (float)h;
}
static __device__ __forceinline__ float4 fp8x4_to_f32(unsigned v) {
#if __has_builtin(__builtin_amdgcn_cvt_pk_f32_fp8)
    f32x2 lo = __builtin_amdgcn_cvt_pk_f32_fp8(v, false);
    f32x2 hi = __builtin_amdgcn_cvt_pk_f32_fp8(v, true);
    return make_float4(lo[0], lo[1], hi[0], hi[1]);
#else
    return make_float4(fp82f_sw((unsigned char)(v & 0xFF)),
                       fp82f_sw((unsigned char)((v >> 8) & 0xFF)),
                       fp82f_sw((unsigned char)((v >> 16) & 0xFF)),
                       fp82f_sw((unsigned char)(v >> 24)));
#endif
}

// partition + fused zr8 precompute.
__global__ __launch_bounds__(BLK) void partition2_kernel(const int* __restrict__ ei,
        int* __restrict__ gfill, unsigned* __restrict__ pack,
        int E, int npart, int nbuck, int obits,
        const float4* __restrict__ z4, const float* __restrict__ nf,
        uchar4* __restrict__ zr8, int C, long totalP) {
    __shared__ int lcnt[MAX_BUCKETS];   // pass1 hist, then bump counter
    __shared__ int lbase[MAX_BUCKETS];  // reserved global run base
    for (int k = threadIdx.x; k < nbuck; k += BLK) lcnt[k] = 0;
    __syncthreads();

    // fused precompute slice (independent; hides under hist latency)
    for (long t = (long)blockIdx.x * BLK + threadIdx.x; t < totalP;
         t += (long)npart * BLK) {
        int node = (int)(t / C);
        float s = nf[node];
        float4 v = z4[t];
        uchar4 q;
        q.x = f2fp8(s * v.x); q.y = f2fp8(s * v.y);
        q.z = f2fp8(s * v.z); q.w = f2fp8(s * v.w);
        zr8[t] = q;
    }

    int twoE = 2 * E;
    int base = blockIdx.x * IPB;
    int endt = min(base + IPB, twoE);

    // Pass 1: LDS hist of own records (node column; L2-resident for pass 2).
    for (int t = base + threadIdx.x; t < endt; t += BLK)
        atomicAdd(&lcnt[ei[t] >> RANGE_SHIFT], 1);
    __syncthreads();

    // Reserve one run per non-empty bucket (coalesced global atomics).
    for (int k = threadIdx.x; k < nbuck; k += BLK) {
        int c = lcnt[k];
        lbase[k] = (c > 0) ? atomicAdd(&gfill[k], c) : 0;
        lcnt[k] = 0;                      // reuse as bump
    }
    __syncthreads();

    // Pass 2: place records into the reserved runs (~21-record runs).
    for (int t = base + threadIdx.x; t < endt; t += BLK) {
        int node  = ei[t];
        int other = (t < E) ? ei[t + E] : ei[t - E];
        int bk = node >> RANGE_SHIFT;
        int pos = lbase[bk] + atomicAdd(&lcnt[bk], 1);
        if (pos < CAP)                    // 11-sigma guard (never expected)
            pack[(long)bk * CAP + pos] =
                ((unsigned)(node & (RANGE - 1)) << obits) | (unsigned)other;
    }
}

// Fused: in-LDS counting sort of own bucket region + fp8 register gather + finalize.
__global__ __launch_bounds__(GBLK) void bucket_sort_gather(
        const float4* __restrict__ z4, const unsigned* __restrict__ zr8,
        const float* __restrict__ nf, const unsigned* __restrict__ pack,
        const int* __restrict__ gfill, float4* __restrict__ out4,
        float scale, int N, int C, int nbuck, int obits) {
    __shared__ int adjl[CAP];
    __shared__ int lcnt[RANGE];
    __shared__ int lexc[RANGE];
    __shared__ int ldeg[RANGE];
    __shared__ int sbuf[RANGE];

    int b = blockIdx.x;
    long bstart = (long)b * CAP;
    int bsize = gfill[b];
    if (bsize > CAP) bsize = CAP;
    int tid = threadIdx.x;
    unsigned omask = (1u << obits) - 1u;
    int node0 = b << RANGE_SHIFT;

    if (tid < RANGE) lcnt[tid] = 0;
    __syncthreads();
    // Pass A: hist of node-locals over own region.
    for (int it = tid; it < bsize; it += GBLK)
        atomicAdd(&lcnt[pack[bstart + it] >> obits], 1);
    __syncthreads();
    // Exclusive scan of 256 counters (Hillis-Steele, barriers outside guards).
    if (tid < RANGE) sbuf[tid] = lcnt[tid];
    __syncthreads();
    for (int off = 1; off < RANGE; off <<= 1) {
        int v = 0, u = 0;
        if (tid < RANGE) { v = sbuf[tid]; if (tid >= off) u = sbuf[tid - off]; }
        __syncthreads();
        if (tid < RANGE) sbuf[tid] = v + u;
        __syncthreads();
    }
    if (tid < RANGE) {
        int inc = sbuf[tid], d = lcnt[tid];
        lexc[tid] = inc - d;
        ldeg[tid] = d;
        lcnt[tid] = 0;                    // reuse as bump
    }
    __syncthreads();
    // Pass B: place into per-node adjacency (L2-hot re-read).
    for (int it = tid; it < bsize; it += GBLK) {
        unsigned pk = pack[bstart + it];
        int il = (int)(pk >> obits);
        int r = atomicAdd(&lcnt[il], 1);
        adjl[lexc[il] + r] = (int)(pk & omask);
    }
    __syncthreads();
    // Pass C: register gather + fused finalize. RANGE*12 = 3072 tasks.
    for (int task = tid; task < RANGE * 12; task += GBLK) {
        int nl = task / 12;
        int c  = task - nl * 12;
        int node = node0 + nl;
        if (node >= N) continue;
        int s  = lexc[nl];
        int dg = ldeg[nl];
        float4 sum = make_float4(0.f, 0.f, 0.f, 0.f);
        #pragma unroll 4
        for (int k = 0; k < dg; ++k) {
            int j = adjl[s + k];
            float4 v = fp8x4_to_f32(zr8[(long)j * C + c]);
            sum.x += v.x; sum.y += v.y; sum.z += v.z; sum.w += v.w;
        }
        float nfi = nf[node];
        float4 zi = z4[(long)node * C + c];
        float a   = scale * nfi;
        float dn  = (float)dg * nfi;
        float4 o;
        o.x = zi.x - a * (dn * zi.x - sum.x);
        o.y = zi.y - a * (dn * zi.y - sum.y);
        o.z = zi.z - a * (dn * zi.z - sum.z);
        o.w = zi.w - a * (dn * zi.w - sum.w);
        out4[(long)node * C + c] = o;
    }
}

// ---- fallback (round-1 atomic path) ----
__global__ void edge_scatter_kernel(const float* __restrict__ z, const int* __restrict__ ei,
                                    const float* __restrict__ nf, float* __restrict__ acc,
                                    int E, int D, long total) {
    long idx = (long)blockIdx.x * blockDim.x + threadIdx.x;
    if (idx >= total) return;
    int e = (int)(idx / D);
    int d = (int)(idx - (long)e * D);
    int r = ei[e];
    int c = ei[E + e];
    float diff = nf[r] * z[(long)r * D + d] - nf[c] * z[(long)c * D + d];
    atomicAdd(&acc[(long)r * D + d],  diff);
    atomicAdd(&acc[(long)c * D + d], -diff);
}
__global__ void finalize_kernel(const float* __restrict__ z, const float* __restrict__ nf,
                                float* __restrict__ out, float scale, int D, long total) {
    long i = (long)blockIdx.x * blockDim.x + threadIdx.x;
    if (i >= total) return;
    int node = (int)(i / D);
    out[i] = z[i] - scale * nf[node] * out[i];
}

extern "C" void kernel_launch(void* const* d_in, const int* in_sizes, int n_in,
                              void* d_out, int out_size, void* d_ws, size_t ws_size,
                              hipStream_t stream) {
    const float* z  = (const float*)d_in[0];
    const int*   ei = (const int*)d_in[2];
    const float* nf = (const float*)d_in[3];
    float* out = (float*)d_out;

    const int ND = in_sizes[0];
    const int Nn = in_sizes[3];
    const int D  = ND / Nn;
    const int E  = in_sizes[2] / 2;
    const int twoE = 2 * E;
    const float scale = 0.1f * 2.0f / (float)Nn;

    int obits = 1;
    while ((1 << obits) < Nn) obits++;
    const int nbuck = (Nn + RANGE - 1) >> RANGE_SHIFT;   // 391
    const int npart = (twoE + IPB - 1) / IPB;            // 391

    auto align_up = [](size_t x) { return (x + 255) & ~(size_t)255; };
    size_t off_gfill = 0;
    size_t off_pack  = off_gfill + align_up((size_t)nbuck * 4);
    size_t off_zr8   = off_pack  + align_up((size_t)nbuck * CAP * 4);
    size_t need      = off_zr8   + align_up((size_t)ND);

    // mean bucket size must leave >= ~10 sigma headroom under CAP
    bool ok = (D == 48) && (nbuck <= MAX_BUCKETS) && (obits + RANGE_SHIFT <= 32) &&
              (twoE / nbuck <= CAP - 1000) && (ws_size >= need);

    if (!ok) {
        hipMemsetAsync(out, 0, (size_t)ND * sizeof(float), stream);
        const long totalE = (long)E * D;
        edge_scatter_kernel<<<(int)((totalE + 255) / 256), 256, 0, stream>>>(
            z, ei, nf, out, E, D, totalE);
        finalize_kernel<<<(ND + 255) / 256, 256, 0, stream>>>(
            z, nf, out, scale, D, (long)ND);
        return;
    }

    char* w = (char*)d_ws;
    int*      gfill = (int*)(w + off_gfill);
    unsigned* pack  = (unsigned*)(w + off_pack);
    uchar4*   zr8   = (uchar4*)(w + off_zr8);

    const int C = D / 4;                 // 12
    long totalP = (long)Nn * C;

    hipMemsetAsync(gfill, 0, (size_t)nbuck * 4, stream);
    partition2_kernel<<<npart, BLK, 0, stream>>>(ei, gfill, pack, E, npart, nbuck,
                                                 obits, (const float4*)z, nf, zr8, C, totalP);
    bucket_sort_gather<<<nbuck, GBLK, 0, stream>>>(
        (const float4*)z, (const unsigned*)zr8, nf, pack, gfill, (float4*)out,
        scale, Nn, C, nbuck, obits);
}

// Round 14
// 84.232 us; speedup vs baseline: 1.6171x; 1.1023x over previous
//
#include <hip/hip_runtime.h>
#include <hip/hip_fp8.h>

// out[i] = z[i] - COEFF*(2/N)*nf[i]*g[i],  g[i] = deg(i)*zr[i] - sum_{adj} zr[j],
// zr[j] = nf[j]*z[j].  adj counts both edge directions.
//
// 3-dispatch pipeline (fixed-stride bucket regions, no count/scan):
//  0) memset gfill (391 ints)
//  1) partition2 (+fused fp8 zr precompute): 256 blocks x 1024 thr
//     (1 block/CU, 16 waves/CU, perfectly balanced grid — r13 had 391 blocks
//     -> 2-vs-1 block CU imbalance at 25% occupancy). Per-block LDS hist of
//     node>>8, ONE global atomicAdd per (block,bucket) reserves a run, then
//     run writes (LDS bump). IPB=12500 -> runs ~32 records (128B).
//  2) bucket_sort_gather (1024 thr): block per 256-node bucket; LDS counting
//     sort of its region -> per-node adjacency, register fp8 gather + finalize.

#define RANGE_SHIFT 8
#define RANGE 256
#define NPART 256
#define MAX_BUCKETS 512
#define CAP 9216
#define PBLK 1024
#define GBLK 1024

typedef float f32x2 __attribute__((ext_vector_type(2)));

static __device__ __forceinline__ unsigned char f2fp8(float f) {
    __hip_fp8_e4m3 h(f);
    return (unsigned char)h.__x;
}
static __device__ __forceinline__ float fp82f_sw(unsigned char b) {
    __hip_fp8_e4m3 h; h.__x = (__hip_fp8_storage_t)b; return (float)h;
}
static __device__ __forceinline__ float4 fp8x4_to_f32(unsigned v) {
#if __has_builtin(__builtin_amdgcn_cvt_pk_f32_fp8)
    f32x2 lo = __builtin_amdgcn_cvt_pk_f32_fp8(v, false);
    f32x2 hi = __builtin_amdgcn_cvt_pk_f32_fp8(v, true);
    return make_float4(lo[0], lo[1], hi[0], hi[1]);
#else
    return make_float4(fp82f_sw((unsigned char)(v & 0xFF)),
                       fp82f_sw((unsigned char)((v >> 8) & 0xFF)),
                       fp82f_sw((unsigned char)((v >> 16) & 0xFF)),
                       fp82f_sw((unsigned char)(v >> 24)));
#endif
}

// partition + fused zr8 precompute. 256 blocks x 1024 threads.
__global__ __launch_bounds__(PBLK) void partition2_kernel(const int* __restrict__ ei,
        int* __restrict__ gfill, unsigned* __restrict__ pack,
        int E, int ipb, int nbuck, int obits,
        const float4* __restrict__ z4, const float* __restrict__ nf,
        uchar4* __restrict__ zr8, int C, long totalP) {
    __shared__ int lcnt[MAX_BUCKETS];   // pass1 hist, then bump counter
    __shared__ int lbase[MAX_BUCKETS];  // reserved global run base
    for (int k = threadIdx.x; k < nbuck; k += PBLK) lcnt[k] = 0;
    __syncthreads();

    // fused precompute slice (independent; hides under hist latency)
    for (long t = (long)blockIdx.x * PBLK + threadIdx.x; t < totalP;
         t += (long)NPART * PBLK) {
        int node = (int)(t / C);
        float s = nf[node];
        float4 v = z4[t];
        uchar4 q;
        q.x = f2fp8(s * v.x); q.y = f2fp8(s * v.y);
        q.z = f2fp8(s * v.z); q.w = f2fp8(s * v.w);
        zr8[t] = q;
    }

    int twoE = 2 * E;
    int base = blockIdx.x * ipb;
    int endt = min(base + ipb, twoE);

    // Pass 1: LDS hist of own records (node column; L2-resident for pass 2).
    for (int t = base + threadIdx.x; t < endt; t += PBLK)
        atomicAdd(&lcnt[ei[t] >> RANGE_SHIFT], 1);
    __syncthreads();

    // Reserve one run per non-empty bucket (coalesced global atomics).
    for (int k = threadIdx.x; k < nbuck; k += PBLK) {
        int c = lcnt[k];
        lbase[k] = (c > 0) ? atomicAdd(&gfill[k], c) : 0;
        lcnt[k] = 0;                      // reuse as bump
    }
    __syncthreads();

    // Pass 2: place records into the reserved runs (~32-record / 128B runs).
    for (int t = base + threadIdx.x; t < endt; t += PBLK) {
        int node  = ei[t];
        int other = (t < E) ? ei[t + E] : ei[t - E];
        int bk = node >> RANGE_SHIFT;
        int pos = lbase[bk] + atomicAdd(&lcnt[bk], 1);
        if (pos < CAP)                    // 11-sigma guard (never expected)
            pack[(long)bk * CAP + pos] =
                ((unsigned)(node & (RANGE - 1)) << obits) | (unsigned)other;
    }
}

// Fused: in-LDS counting sort of own bucket region + fp8 register gather + finalize.
__global__ __launch_bounds__(GBLK) void bucket_sort_gather(
        const float4* __restrict__ z4, const unsigned* __restrict__ zr8,
        const float* __restrict__ nf, const unsigned* __restrict__ pack,
        const int* __restrict__ gfill, float4* __restrict__ out4,
        float scale, int N, int C, int nbuck, int obits) {
    __shared__ int adjl[CAP];
    __shared__ int lcnt[RANGE];
    __shared__ int lexc[RANGE];
    __shared__ int ldeg[RANGE];
    __shared__ int sbuf[RANGE];

    int b = blockIdx.x;
    long bstart = (long)b * CAP;
    int bsize = gfill[b];
    if (bsize > CAP) bsize = CAP;
    int tid = threadIdx.x;
    unsigned omask = (1u << obits) - 1u;
    int node0 = b << RANGE_SHIFT;

    if (tid < RANGE) lcnt[tid] = 0;
    __syncthreads();
    // Pass A: hist of node-locals over own region.
    for (int it = tid; it < bsize; it += GBLK)
        atomicAdd(&lcnt[pack[bstart + it] >> obits], 1);
    __syncthreads();
    // Exclusive scan of 256 counters (Hillis-Steele, barriers outside guards).
    if (tid < RANGE) sbuf[tid] = lcnt[tid];
    __syncthreads();
    for (int off = 1; off < RANGE; off <<= 1) {
        int v = 0, u = 0;
        if (tid < RANGE) { v = sbuf[tid]; if (tid >= off) u = sbuf[tid - off]; }
        __syncthreads();
        if (tid < RANGE) sbuf[tid] = v + u;
        __syncthreads();
    }
    if (tid < RANGE) {
        int inc = sbuf[tid], d = lcnt[tid];
        lexc[tid] = inc - d;
        ldeg[tid] = d;
        lcnt[tid] = 0;                    // reuse as bump
    }
    __syncthreads();
    // Pass B: place into per-node adjacency (L2-hot re-read).
    for (int it = tid; it < bsize; it += GBLK) {
        unsigned pk = pack[bstart + it];
        int il = (int)(pk >> obits);
        int r = atomicAdd(&lcnt[il], 1);
        adjl[lexc[il] + r] = (int)(pk & omask);
    }
    __syncthreads();
    // Pass C: register gather + fused finalize. RANGE*12 = 3072 tasks.
    for (int task = tid; task < RANGE * 12; task += GBLK) {
        int nl = task / 12;
        int c  = task - nl * 12;
        int node = node0 + nl;
        if (node >= N) continue;
        int s  = lexc[nl];
        int dg = ldeg[nl];
        float4 sum = make_float4(0.f, 0.f, 0.f, 0.f);
        #pragma unroll 4
        for (int k = 0; k < dg; ++k) {
            int j = adjl[s + k];
            float4 v = fp8x4_to_f32(zr8[(long)j * C + c]);
            sum.x += v.x; sum.y += v.y; sum.z += v.z; sum.w += v.w;
        }
        float nfi = nf[node];
        float4 zi = z4[(long)node * C + c];
        float a   = scale * nfi;
        float dn  = (float)dg * nfi;
        float4 o;
        o.x = zi.x - a * (dn * zi.x - sum.x);
        o.y = zi.y - a * (dn * zi.y - sum.y);
        o.z = zi.z - a * (dn * zi.z - sum.z);
        o.w = zi.w - a * (dn * zi.w - sum.w);
        out4[(long)node * C + c] = o;
    }
}

// ---- fallback (round-1 atomic path) ----
__global__ void edge_scatter_kernel(const float* __restrict__ z, const int* __restrict__ ei,
                                    const float* __restrict__ nf, float* __restrict__ acc,
                                    int E, int D, long total) {
    long idx = (long)blockIdx.x * blockDim.x + threadIdx.x;
    if (idx >= total) return;
    int e = (int)(idx / D);
    int d = (int)(idx - (long)e * D);
    int r = ei[e];
    int c = ei[E + e];
    float diff = nf[r] * z[(long)r * D + d] - nf[c] * z[(long)c * D + d];
    atomicAdd(&acc[(long)r * D + d],  diff);
    atomicAdd(&acc[(long)c * D + d], -diff);
}
__global__ void finalize_kernel(const float* __restrict__ z, const float* __restrict__ nf,
                                float* __restrict__ out, float scale, int D, long total) {
    long i = (long)blockIdx.x * blockDim.x + threadIdx.x;
    if (i >= total) return;
    int node = (int)(i / D);
    out[i] = z[i] - scale * nf[node] * out[i];
}

extern "C" void kernel_launch(void* const* d_in, const int* in_sizes, int n_in,
                              void* d_out, int out_size, void* d_ws, size_t ws_size,
                              hipStream_t stream) {
    const float* z  = (const float*)d_in[0];
    const int*   ei = (const int*)d_in[2];
    const float* nf = (const float*)d_in[3];
    float* out = (float*)d_out;

    const int ND = in_sizes[0];
    const int Nn = in_sizes[3];
    const int D  = ND / Nn;
    const int E  = in_sizes[2] / 2;
    const int twoE = 2 * E;
    const float scale = 0.1f * 2.0f / (float)Nn;

    int obits = 1;
    while ((1 << obits) < Nn) obits++;
    const int nbuck = (Nn + RANGE - 1) >> RANGE_SHIFT;   // 391
    const int ipb = (twoE + NPART - 1) / NPART;          // 12500

    auto align_up = [](size_t x) { return (x + 255) & ~(size_t)255; };
    size_t off_gfill = 0;
    size_t off_pack  = off_gfill + align_up((size_t)nbuck * 4);
    size_t off_zr8   = off_pack  + align_up((size_t)nbuck * CAP * 4);
    size_t need      = off_zr8   + align_up((size_t)ND);

    // mean bucket size must leave >= ~10 sigma headroom under CAP
    bool ok = (D == 48) && (nbuck <= MAX_BUCKETS) && (obits + RANGE_SHIFT <= 32) &&
              (twoE / nbuck <= CAP - 1000) && (ws_size >= need);

    if (!ok) {
        hipMemsetAsync(out, 0, (size_t)ND * sizeof(float), stream);
        const long totalE = (long)E * D;
        edge_scatter_kernel<<<(int)((totalE + 255) / 256), 256, 0, stream>>>(
            z, ei, nf, out, E, D, totalE);
        finalize_kernel<<<(ND + 255) / 256, 256, 0, stream>>>(
            z, nf, out, scale, D, (long)ND);
        return;
    }

    char* w = (char*)d_ws;
    int*      gfill = (int*)(w + off_gfill);
    unsigned* pack  = (unsigned*)(w + off_pack);
    uchar4*   zr8   = (uchar4*)(w + off_zr8);

    const int C = D / 4;                 // 12
    long totalP = (long)Nn * C;

    hipMemsetAsync(gfill, 0, (size_t)nbuck * 4, stream);
    partition2_kernel<<<NPART, PBLK, 0, stream>>>(ei, gfill, pack, E, ipb, nbuck,
                                                  obits, (const float4*)z, nf, zr8, C, totalP);
    bucket_sort_gather<<<nbuck, GBLK, 0, stream>>>(
        (const float4*)z, (const unsigned*)zr8, nf, pack, gfill, (float4*)out,
        scale, Nn, C, nbuck, obits);
}